// Round 3
// baseline (360.049 us; speedup 1.0000x reference)
//
#include <hip/hip_runtime.h>
#include <hip/hip_bf16.h>
#include <math.h>

#define B_ 4
#define S_ 4096
#define DM_ 1024
#define DH_ 1024
#define M_ (B_*S_)      // 16384
#define K_ 1024
#define N1_ 3072
#define CHUNKS 64
#define CLEN 64         // S_/CHUNKS
#define NCH 4096        // B_*DH_

typedef short bf16x8 __attribute__((ext_vector_type(8)));
typedef float f32x4 __attribute__((ext_vector_type(4)));

static __device__ __forceinline__ unsigned short f2b(float f) {
  unsigned u = __float_as_uint(f);
  unsigned rounding = 0x7fffu + ((u >> 16) & 1u);
  return (unsigned short)((u + rounding) >> 16);
}
static __device__ __forceinline__ float b2f(unsigned short u) {
  return __uint_as_float(((unsigned)u) << 16);
}

// fast activations: v_exp_f32 + v_rcp_f32 (~1e-6 rel err, << bf16 rounding)
static __device__ __forceinline__ float fast_exp(float x) {
  return __builtin_amdgcn_exp2f(x * 1.4426950408889634f);
}
static __device__ __forceinline__ float fast_sigmoid(float x) {
  return __builtin_amdgcn_rcpf(1.0f + fast_exp(-x));
}
static __device__ __forceinline__ float fast_tanh(float x) {
  return 2.0f * __builtin_amdgcn_rcpf(1.0f + fast_exp(-2.0f * x)) - 1.0f;
}

// ---------- convert x (fp32 -> bf16), 4 elems/thread ----------
__global__ void cvt_x_kernel(const float* __restrict__ x, unsigned short* __restrict__ xb) {
  int i = blockIdx.x * blockDim.x + threadIdx.x;
  float4 v = reinterpret_cast<const float4*>(x)[i];
  ushort4 o;
  o.x = f2b(v.x); o.y = f2b(v.y); o.z = f2b(v.z); o.w = f2b(v.w);
  reinterpret_cast<ushort4*>(xb)[i] = o;
}

// ---------- transpose + convert: in (R x C) fp32 -> out (C x R) bf16 ----------
__global__ void transpose_cvt_kernel(const float* __restrict__ in, unsigned short* __restrict__ out,
                                     int R, int C) {
  __shared__ float tile[32][33];
  int c0 = blockIdx.x * 32, r0 = blockIdx.y * 32;
  int tx = threadIdx.x & 31, ty = threadIdx.x >> 5;  // ty 0..7
#pragma unroll
  for (int i = 0; i < 32; i += 8)
    tile[ty + i][tx] = in[(size_t)(r0 + ty + i) * C + (c0 + tx)];
  __syncthreads();
#pragma unroll
  for (int i = 0; i < 32; i += 8)
    out[(size_t)(c0 + ty + i) * R + (r0 + tx)] = f2b(tile[tx][ty + i]);
}

// ---------- GEMM: A (M x K) bf16 row-major, Bt (N x K) bf16 (B transposed) ----------
// LDS layout XOR-swizzled: 16B chunk at (row, c) holds global chunk c ^ ((row>>1)&3)
// -> ds_read_b128 fragment loads are bank-conflict-free (verified R2: conflicts 1.26e7 -> 0).
// mode 1: N=3072, epilogue tanh/sigmoid -> bf16 into dst0/dst1/dst2 (each M x 1024)
// mode 0: N=1024, epilogue fp32 + bias -> dstf (M x 1024)
#define GLDS16(g, l) \
  __builtin_amdgcn_global_load_lds((const __attribute__((address_space(1))) void*)(g), \
                                   (__attribute__((address_space(3))) void*)(l), 16, 0, 0)

__global__ __launch_bounds__(256, 4) void gemm_act_kernel(
    const unsigned short* __restrict__ A,
    const unsigned short* __restrict__ Bt,
    const float* __restrict__ bias,
    unsigned short* __restrict__ dst0,
    unsigned short* __restrict__ dst1,
    unsigned short* __restrict__ dst2,
    float* __restrict__ dstf,
    int mode) {
  __shared__ __align__(16) unsigned short As[128 * 32];
  __shared__ __align__(16) unsigned short Bs[128 * 32];
  const int tid = threadIdx.x;
  const int lane = tid & 63;
  const int w = tid >> 6;            // wave 0..3
  const int wm = w & 1, wn = w >> 1; // 2x2 wave grid, each wave 64x64
  const int q = lane >> 4, r16 = lane & 15;
  const int tileM = blockIdx.y * 128;
  const int tileN = blockIdx.x * 128;

  const int srow = lane >> 2;                                  // 0..15
  const int schunk = (((lane & 3) ^ ((lane >> 3) & 3)) * 8);   // swizzled global chunk
  const int rsw = (r16 >> 1) & 3;                              // read-side swizzle

  f32x4 zero = {0.f, 0.f, 0.f, 0.f};
  f32x4 acc[4][4];
#pragma unroll
  for (int i = 0; i < 4; ++i)
#pragma unroll
    for (int j = 0; j < 4; ++j) acc[i][j] = zero;

  for (int kt = 0; kt < K_; kt += 32) {
    // stage A (128x32) and Bt (128x32): 4 waves x 2 parts x 1KB each
#pragma unroll
    for (int p = 0; p < 2; ++p) {
      int row = w * 32 + p * 16;  // wave-uniform
      GLDS16(A + (size_t)(tileM + row + srow) * K_ + kt + schunk, &As[row * 32]);
      GLDS16(Bt + (size_t)(tileN + row + srow) * K_ + kt + schunk, &Bs[row * 32]);
    }
    __syncthreads();

    bf16x8 af[4], bfr[4];
#pragma unroll
    for (int i = 0; i < 4; ++i)
      af[i] = *(const bf16x8*)&As[(wm * 64 + i * 16 + r16) * 32 + (q ^ rsw) * 8];
#pragma unroll
    for (int j = 0; j < 4; ++j)
      bfr[j] = *(const bf16x8*)&Bs[(wn * 64 + j * 16 + r16) * 32 + (q ^ rsw) * 8];
#pragma unroll
    for (int i = 0; i < 4; ++i)
#pragma unroll
      for (int j = 0; j < 4; ++j)
        acc[i][j] = __builtin_amdgcn_mfma_f32_16x16x32_bf16(af[i], bfr[j], acc[i][j], 0, 0, 0);
    __syncthreads();
  }

  // epilogue: C/D layout col = lane&15, row = (lane>>4)*4 + reg  [m89]
  if (mode == 1) {
    int cls = tileN >> 10;  // 0: tanh->dst0, 1: sigmoid->dst1, 2: sigmoid->dst2
    unsigned short* dst = (cls == 0) ? dst0 : ((cls == 1) ? dst1 : dst2);
    int ncol0 = tileN & 1023;
#pragma unroll
    for (int i = 0; i < 4; ++i) {
#pragma unroll
      for (int j = 0; j < 4; ++j) {
        int nl = wn * 64 + j * 16 + r16;
        float bb = bias[tileN + nl];
#pragma unroll
        for (int r = 0; r < 4; ++r) {
          int m = tileM + wm * 64 + i * 16 + q * 4 + r;
          float u = acc[i][j][r] + bb;
          float v = (cls == 0) ? fast_tanh(u) : fast_sigmoid(u);
          dst[(size_t)m * 1024 + (ncol0 + nl)] = f2b(v);
        }
      }
    }
  } else {
#pragma unroll
    for (int i = 0; i < 4; ++i) {
#pragma unroll
      for (int j = 0; j < 4; ++j) {
        int nl = wn * 64 + j * 16 + r16;
        float bb = bias[tileN + nl];
#pragma unroll
        for (int r = 0; r < 4; ++r) {
          int m = tileM + wm * 64 + i * 16 + q * 4 + r;
          dstf[(size_t)m * 1024 + tileN + nl] = acc[i][j][r] + bb;
        }
      }
    }
  }
}

// ---------- scan pass A: per (b, chunk, 256-channel group) compute (prodF, localScan) ----------
__global__ void scanA_kernel(const unsigned short* __restrict__ a0,
                             const unsigned short* __restrict__ a1,
                             float* __restrict__ cF, float* __restrict__ cS) {
  int bid = blockIdx.x;
  int dhb = bid & 3;
  int j = (bid >> 2) & 63;
  int b = bid >> 8;
  int dh = dhb * 256 + threadIdx.x;
  size_t base = ((size_t)b * S_ + (size_t)j * CLEN) * DH_ + dh;
  float F = 1.f, Sv = 0.f;
#pragma unroll 4
  for (int t = 0; t < CLEN; ++t) {
    float inp = b2f(a0[base + (size_t)t * DH_]);
    float ig = b2f(a1[base + (size_t)t * DH_]);
    float f = 1.f - ig;
    F *= f;
    Sv = f * Sv + inp * ig;
  }
  int ch = b * DH_ + dh;
  cF[j * NCH + ch] = F;
  cS[j * NCH + ch] = Sv;
}

// ---------- scan pass B: sequential combine over chunks; emits carry-in per chunk + h_last ----------
__global__ void scanB_kernel(const float* __restrict__ cF, const float* __restrict__ cS,
                             float* __restrict__ cIn, float* __restrict__ hlast) {
  int ch = blockIdx.x * blockDim.x + threadIdx.x;  // 0..4095
  float h = 0.f;
#pragma unroll 4
  for (int j = 0; j < CHUNKS; ++j) {
    cIn[j * NCH + ch] = h;
    h = cF[j * NCH + ch] * h + cS[j * NCH + ch];
  }
  hlast[ch] = h;  // output 0: h[:, -1, :]
}

// ---------- scan pass C: recompute with carry-in, y = tanh(h)*og -> bf16 ----------
__global__ void scanC_kernel(const unsigned short* __restrict__ a0,
                             const unsigned short* __restrict__ a1,
                             const unsigned short* __restrict__ a2,
                             const float* __restrict__ cIn,
                             unsigned short* __restrict__ yb) {
  int bid = blockIdx.x;
  int dhb = bid & 3;
  int j = (bid >> 2) & 63;
  int b = bid >> 8;
  int dh = dhb * 256 + threadIdx.x;
  int ch = b * DH_ + dh;
  size_t base = ((size_t)b * S_ + (size_t)j * CLEN) * DH_ + dh;
  float h = cIn[j * NCH + ch];
#pragma unroll 4
  for (int t = 0; t < CLEN; ++t) {
    size_t idx = base + (size_t)t * DH_;
    float inp = b2f(a0[idx]);
    float ig = b2f(a1[idx]);
    float og = b2f(a2[idx]);
    float f = 1.f - ig;
    h = f * h + inp * ig;
    yb[idx] = f2b(fast_tanh(h) * og);
  }
}

extern "C" void kernel_launch(void* const* d_in, const int* in_sizes, int n_in,
                              void* d_out, int out_size, void* d_ws, size_t ws_size,
                              hipStream_t stream) {
  const float* x = (const float*)d_in[0];
  const float* Wp = (const float*)d_in[1];
  const float* bp = (const float*)d_in[2];
  const float* Wo = (const float*)d_in[3];
  const float* bo = (const float*)d_in[4];
  float* out = (float*)d_out;

  char* w = (char*)d_ws;
  unsigned short* xb = (unsigned short*)w;  w += (size_t)M_ * K_ * 2;       // 32 MiB
  unsigned short* wpt = (unsigned short*)w; w += (size_t)N1_ * K_ * 2;      // 6 MiB
  unsigned short* wot = (unsigned short*)w; w += (size_t)DM_ * K_ * 2;      // 2 MiB
  unsigned short* a0 = (unsigned short*)w;  w += (size_t)M_ * DH_ * 2;      // 32 MiB
  unsigned short* a1 = (unsigned short*)w;  w += (size_t)M_ * DH_ * 2;
  unsigned short* a2 = (unsigned short*)w;  w += (size_t)M_ * DH_ * 2;
  float* cF = (float*)w;  w += (size_t)NCH * CHUNKS * 4;                    // 1 MiB
  float* cS = (float*)w;  w += (size_t)NCH * CHUNKS * 4;
  float* cIn = (float*)w; w += (size_t)NCH * CHUNKS * 4;
  unsigned short* yb = xb;  // alias: xb dead after GEMM1

  cvt_x_kernel<<<(M_ * K_ / 4) / 256, 256, 0, stream>>>(x, xb);
  transpose_cvt_kernel<<<dim3(N1_ / 32, K_ / 32), 256, 0, stream>>>(Wp, wpt, K_, N1_);
  transpose_cvt_kernel<<<dim3(DM_ / 32, DH_ / 32), 256, 0, stream>>>(Wo, wot, DH_, DM_);

  gemm_act_kernel<<<dim3(N1_ / 128, M_ / 128), 256, 0, stream>>>(
      xb, wpt, bp, a0, a1, a2, nullptr, 1);

  scanA_kernel<<<B_ * CHUNKS * (DH_ / 256), 256, 0, stream>>>(a0, a1, cF, cS);
  scanB_kernel<<<NCH / 256, 256, 0, stream>>>(cF, cS, cIn, out);
  scanC_kernel<<<B_ * CHUNKS * (DH_ / 256), 256, 0, stream>>>(a0, a1, a2, cIn, yb);

  gemm_act_kernel<<<dim3(DM_ / 128, M_ / 128), 256, 0, stream>>>(
      yb, wot, bo, nullptr, nullptr, nullptr, out + 4096, 0);
}

// Round 4
// 336.127 us; speedup vs baseline: 1.0712x; 1.0712x over previous
//
#include <hip/hip_runtime.h>
#include <hip/hip_bf16.h>
#include <math.h>

#define B_ 4
#define S_ 4096
#define DM_ 1024
#define DH_ 1024
#define M_ (B_*S_)      // 16384
#define K_ 1024
#define N1_ 3072
#define CHUNKS 64
#define CLEN 64         // S_/CHUNKS
#define NCH 4096        // B_*DH_

typedef short bf16x8 __attribute__((ext_vector_type(8)));
typedef float f32x4 __attribute__((ext_vector_type(4)));

static __device__ __forceinline__ unsigned short f2b(float f) {
  unsigned u = __float_as_uint(f);
  unsigned rounding = 0x7fffu + ((u >> 16) & 1u);
  return (unsigned short)((u + rounding) >> 16);
}
static __device__ __forceinline__ float b2f(unsigned short u) {
  return __uint_as_float(((unsigned)u) << 16);
}

// fast activations: v_exp_f32 + v_rcp_f32 (~1e-6 rel err, << bf16 rounding)
static __device__ __forceinline__ float fast_exp(float x) {
  return __builtin_amdgcn_exp2f(x * 1.4426950408889634f);
}
static __device__ __forceinline__ float fast_sigmoid(float x) {
  return __builtin_amdgcn_rcpf(1.0f + fast_exp(-x));
}
static __device__ __forceinline__ float fast_tanh(float x) {
  return 2.0f * __builtin_amdgcn_rcpf(1.0f + fast_exp(-2.0f * x)) - 1.0f;
}

// ---------- convert x (fp32 -> bf16), 4 elems/thread ----------
__global__ void cvt_x_kernel(const float* __restrict__ x, unsigned short* __restrict__ xb) {
  int i = blockIdx.x * blockDim.x + threadIdx.x;
  float4 v = reinterpret_cast<const float4*>(x)[i];
  ushort4 o;
  o.x = f2b(v.x); o.y = f2b(v.y); o.z = f2b(v.z); o.w = f2b(v.w);
  reinterpret_cast<ushort4*>(xb)[i] = o;
}

// ---------- transpose + convert: in (R x C) fp32 -> out (C x R) bf16 ----------
__global__ void transpose_cvt_kernel(const float* __restrict__ in, unsigned short* __restrict__ out,
                                     int R, int C) {
  __shared__ float tile[32][33];
  int c0 = blockIdx.x * 32, r0 = blockIdx.y * 32;
  int tx = threadIdx.x & 31, ty = threadIdx.x >> 5;  // ty 0..7
#pragma unroll
  for (int i = 0; i < 32; i += 8)
    tile[ty + i][tx] = in[(size_t)(r0 + ty + i) * C + (c0 + tx)];
  __syncthreads();
#pragma unroll
  for (int i = 0; i < 32; i += 8)
    out[(size_t)(c0 + ty + i) * R + (r0 + tx)] = f2b(tile[tx][ty + i]);
}

// ---------- GEMM: A (M x K) bf16 row-major, Bt (N x K) bf16 (B transposed) ----------
// BK=64: halves barrier-drain events vs BK=32 (the structural stall). LDS 2x16 KB.
// 8-chunk XOR swizzle: logical 16B chunk c of row r stored at physical c^(r&7).
//   - staging source swizzle ((lane&7)^(lane>>3)) is base-row independent -> GLDS
//     wave-uniform-base constraint holds.
//   - ds_read_b128: within each 16-lane phase q is constant -> chunks span all 8
//     bank groups x2 = 2-way = free [m136].
// mode 1: N=3072, epilogue tanh/sigmoid -> bf16 into dst0/dst1/dst2 (each M x 1024)
// mode 0: N=1024, epilogue fp32 + bias -> dstf (M x 1024)
#define GLDS16(g, l) \
  __builtin_amdgcn_global_load_lds((const __attribute__((address_space(1))) void*)(g), \
                                   (__attribute__((address_space(3))) void*)(l), 16, 0, 0)

__global__ __launch_bounds__(256, 3) void gemm_act_kernel(
    const unsigned short* __restrict__ A,
    const unsigned short* __restrict__ Bt,
    const float* __restrict__ bias,
    unsigned short* __restrict__ dst0,
    unsigned short* __restrict__ dst1,
    unsigned short* __restrict__ dst2,
    float* __restrict__ dstf,
    int mode) {
  __shared__ __align__(16) unsigned short As[128 * 64];
  __shared__ __align__(16) unsigned short Bs[128 * 64];
  const int tid = threadIdx.x;
  const int lane = tid & 63;
  const int w = tid >> 6;            // wave 0..3
  const int wm = w & 1, wn = w >> 1; // 2x2 wave grid, each wave 64x64
  const int q = lane >> 4, r16 = lane & 15;
  const int tileM = blockIdx.y * 128;
  const int tileN = blockIdx.x * 128;

  const int srow = lane >> 3;                                  // 0..7
  const int schunk = (((lane & 7) ^ (lane >> 3)) * 8);         // swizzled source chunk

  f32x4 zero = {0.f, 0.f, 0.f, 0.f};
  f32x4 acc[4][4];
#pragma unroll
  for (int i = 0; i < 4; ++i)
#pragma unroll
    for (int j = 0; j < 4; ++j) acc[i][j] = zero;

  for (int kt = 0; kt < K_; kt += 64) {
    // stage A (128x64) and Bt (128x64): 4 waves x 4 calls x 1KB (8 rows) each
#pragma unroll
    for (int p = 0; p < 4; ++p) {
      int row = w * 32 + p * 8;  // wave-uniform
      GLDS16(A + (size_t)(tileM + row + srow) * K_ + kt + schunk, &As[row * 64]);
      GLDS16(Bt + (size_t)(tileN + row + srow) * K_ + kt + schunk, &Bs[row * 64]);
    }
    __syncthreads();

#pragma unroll
    for (int kk = 0; kk < 2; ++kk) {
      bf16x8 af[4], bfr[4];
#pragma unroll
      for (int i = 0; i < 4; ++i) {
        int row = wm * 64 + i * 16 + r16;
        af[i] = *(const bf16x8*)&As[row * 64 + (((kk * 4 + q) ^ (r16 & 7)) * 8)];
      }
#pragma unroll
      for (int j = 0; j < 4; ++j) {
        int row = wn * 64 + j * 16 + r16;
        bfr[j] = *(const bf16x8*)&Bs[row * 64 + (((kk * 4 + q) ^ (r16 & 7)) * 8)];
      }
#pragma unroll
      for (int i = 0; i < 4; ++i)
#pragma unroll
        for (int j = 0; j < 4; ++j)
          acc[i][j] = __builtin_amdgcn_mfma_f32_16x16x32_bf16(af[i], bfr[j], acc[i][j], 0, 0, 0);
    }
    __syncthreads();
  }

  // epilogue: C/D layout col = lane&15, row = (lane>>4)*4 + reg  [m89]
  if (mode == 1) {
    int cls = tileN >> 10;  // 0: tanh->dst0, 1: sigmoid->dst1, 2: sigmoid->dst2
    unsigned short* dst = (cls == 0) ? dst0 : ((cls == 1) ? dst1 : dst2);
    int ncol0 = tileN & 1023;
#pragma unroll
    for (int i = 0; i < 4; ++i) {
#pragma unroll
      for (int j = 0; j < 4; ++j) {
        int nl = wn * 64 + j * 16 + r16;
        float bb = bias[tileN + nl];
#pragma unroll
        for (int r = 0; r < 4; ++r) {
          int m = tileM + wm * 64 + i * 16 + q * 4 + r;
          float u = acc[i][j][r] + bb;
          float v = (cls == 0) ? fast_tanh(u) : fast_sigmoid(u);
          dst[(size_t)m * 1024 + (ncol0 + nl)] = f2b(v);
        }
      }
    }
  } else {
#pragma unroll
    for (int i = 0; i < 4; ++i) {
#pragma unroll
      for (int j = 0; j < 4; ++j) {
        int nl = wn * 64 + j * 16 + r16;
        float bb = bias[tileN + nl];
#pragma unroll
        for (int r = 0; r < 4; ++r) {
          int m = tileM + wm * 64 + i * 16 + q * 4 + r;
          dstf[(size_t)m * 1024 + tileN + nl] = acc[i][j][r] + bb;
        }
      }
    }
  }
}

// ---------- scan pass A: per (b, chunk, 256-channel group) compute (prodF, localScan) ----------
__global__ void scanA_kernel(const unsigned short* __restrict__ a0,
                             const unsigned short* __restrict__ a1,
                             float* __restrict__ cF, float* __restrict__ cS) {
  int bid = blockIdx.x;
  int dhb = bid & 3;
  int j = (bid >> 2) & 63;
  int b = bid >> 8;
  int dh = dhb * 256 + threadIdx.x;
  size_t base = ((size_t)b * S_ + (size_t)j * CLEN) * DH_ + dh;
  float F = 1.f, Sv = 0.f;
#pragma unroll 4
  for (int t = 0; t < CLEN; ++t) {
    float inp = b2f(a0[base + (size_t)t * DH_]);
    float ig = b2f(a1[base + (size_t)t * DH_]);
    float f = 1.f - ig;
    F *= f;
    Sv = f * Sv + inp * ig;
  }
  int ch = b * DH_ + dh;
  cF[j * NCH + ch] = F;
  cS[j * NCH + ch] = Sv;
}

// ---------- scan pass B: sequential combine over chunks; emits carry-in per chunk + h_last ----------
__global__ void scanB_kernel(const float* __restrict__ cF, const float* __restrict__ cS,
                             float* __restrict__ cIn, float* __restrict__ hlast) {
  int ch = blockIdx.x * blockDim.x + threadIdx.x;  // 0..4095
  float h = 0.f;
#pragma unroll 4
  for (int j = 0; j < CHUNKS; ++j) {
    cIn[j * NCH + ch] = h;
    h = cF[j * NCH + ch] * h + cS[j * NCH + ch];
  }
  hlast[ch] = h;  // output 0: h[:, -1, :]
}

// ---------- scan pass C: recompute with carry-in, y = tanh(h)*og -> bf16 ----------
__global__ void scanC_kernel(const unsigned short* __restrict__ a0,
                             const unsigned short* __restrict__ a1,
                             const unsigned short* __restrict__ a2,
                             const float* __restrict__ cIn,
                             unsigned short* __restrict__ yb) {
  int bid = blockIdx.x;
  int dhb = bid & 3;
  int j = (bid >> 2) & 63;
  int b = bid >> 8;
  int dh = dhb * 256 + threadIdx.x;
  int ch = b * DH_ + dh;
  size_t base = ((size_t)b * S_ + (size_t)j * CLEN) * DH_ + dh;
  float h = cIn[j * NCH + ch];
#pragma unroll 4
  for (int t = 0; t < CLEN; ++t) {
    size_t idx = base + (size_t)t * DH_;
    float inp = b2f(a0[idx]);
    float ig = b2f(a1[idx]);
    float og = b2f(a2[idx]);
    float f = 1.f - ig;
    h = f * h + inp * ig;
    yb[idx] = f2b(fast_tanh(h) * og);
  }
}

extern "C" void kernel_launch(void* const* d_in, const int* in_sizes, int n_in,
                              void* d_out, int out_size, void* d_ws, size_t ws_size,
                              hipStream_t stream) {
  const float* x = (const float*)d_in[0];
  const float* Wp = (const float*)d_in[1];
  const float* bp = (const float*)d_in[2];
  const float* Wo = (const float*)d_in[3];
  const float* bo = (const float*)d_in[4];
  float* out = (float*)d_out;

  char* w = (char*)d_ws;
  unsigned short* xb = (unsigned short*)w;  w += (size_t)M_ * K_ * 2;       // 32 MiB
  unsigned short* wpt = (unsigned short*)w; w += (size_t)N1_ * K_ * 2;      // 6 MiB
  unsigned short* wot = (unsigned short*)w; w += (size_t)DM_ * K_ * 2;      // 2 MiB
  unsigned short* a0 = (unsigned short*)w;  w += (size_t)M_ * DH_ * 2;      // 32 MiB
  unsigned short* a1 = (unsigned short*)w;  w += (size_t)M_ * DH_ * 2;
  unsigned short* a2 = (unsigned short*)w;  w += (size_t)M_ * DH_ * 2;
  float* cF = (float*)w;  w += (size_t)NCH * CHUNKS * 4;                    // 1 MiB
  float* cS = (float*)w;  w += (size_t)NCH * CHUNKS * 4;
  float* cIn = (float*)w; w += (size_t)NCH * CHUNKS * 4;
  unsigned short* yb = xb;  // alias: xb dead after GEMM1

  cvt_x_kernel<<<(M_ * K_ / 4) / 256, 256, 0, stream>>>(x, xb);
  transpose_cvt_kernel<<<dim3(N1_ / 32, K_ / 32), 256, 0, stream>>>(Wp, wpt, K_, N1_);
  transpose_cvt_kernel<<<dim3(DM_ / 32, DH_ / 32), 256, 0, stream>>>(Wo, wot, DH_, DM_);

  gemm_act_kernel<<<dim3(N1_ / 128, M_ / 128), 256, 0, stream>>>(
      xb, wpt, bp, a0, a1, a2, nullptr, 1);

  scanA_kernel<<<B_ * CHUNKS * (DH_ / 256), 256, 0, stream>>>(a0, a1, cF, cS);
  scanB_kernel<<<NCH / 256, 256, 0, stream>>>(cF, cS, cIn, out);
  scanC_kernel<<<B_ * CHUNKS * (DH_ / 256), 256, 0, stream>>>(a0, a1, a2, cIn, yb);

  gemm_act_kernel<<<dim3(DM_ / 128, M_ / 128), 256, 0, stream>>>(
      yb, wot, bo, nullptr, nullptr, nullptr, out + 4096, 0);
}